// Round 5
// baseline (1428.690 us; speedup 1.0000x reference)
//
#include <hip/hip_runtime.h>

constexpr int FEAT = 512;          // feature dim
constexpr int NCLS = 50000;        // classes
constexpr int B    = 8192;         // batch
constexpr float ALPHA_F = 0.1f;
constexpr int NBINS = 256;

typedef float f32x4 __attribute__((ext_vector_type(4)));

// ---------------------------------------------------------------------------
// ws layout (4B elems):
//   [0, NCLS)              head (int)   per-class list head, -1 = empty
//   [NCLS, NCLS+B)         next (int)   linked list
//   [NCLS+B, +NBINS)       bins (float) loss partial bins
//   [NCLS+B+NBINS]         done (int)   last-block counter
// ---------------------------------------------------------------------------

// grid exactly B threads; also zeroes bins + done (safe: k_class runs after)
__global__ void k_build(const int* __restrict__ labels,
                        int* __restrict__ head, int* __restrict__ next,
                        float* __restrict__ bins, int* __restrict__ done) {
    int i = blockIdx.x * blockDim.x + threadIdx.x;
    next[i] = atomicExch(&head[labels[i]], i);
    if (i < NBINS) bins[i] = 0.0f;
    if (i == 0) *done = 0;
}

// realigned +1-dword row store (float4 body), cached (let L3 absorb)
__device__ __forceinline__ void store_row(float* __restrict__ orow,
                                          f32x4 n0, f32x4 n1, int lane) {
    const float bx = __shfl(n1.x, 0);
    const float by = __shfl(n1.y, 0);
    const float bz = __shfl(n1.z, 0);
    float x0 = __shfl_down(n0.x, 1), y0 = __shfl_down(n0.y, 1), z0 = __shfl_down(n0.z, 1);
    float x1 = __shfl_down(n1.x, 1), y1 = __shfl_down(n1.y, 1), z1 = __shfl_down(n1.z, 1);
    if (lane == 63) { x0 = bx; y0 = by; z0 = bz; }

    if (lane == 0) { orow[0] = n0.x; orow[1] = n0.y; orow[2] = n0.z; }
    f32x4* oa = (f32x4*)(orow + 3);            // 16B aligned
    oa[lane] = (f32x4){n0.w, x0, y0, z0};
    if (lane < 63)
        oa[64 + lane] = (f32x4){n1.w, x1, y1, z1};
    if (lane == 63) orow[511] = n1.w;
}

// One wave per class; grid = 50000 waves exactly (12500 blocks x 4 waves).
// Fused: EMA center update + loss partial + (last block) final loss reduce.
__global__ void __launch_bounds__(256)
k_class(const float* __restrict__ centers,
        const float* __restrict__ features,
        const int* __restrict__ head,
        const int* __restrict__ next,
        float* __restrict__ out,          // [0]=loss, +1 = new_centers
        float* __restrict__ bins,
        int* __restrict__ done) {
    const int w    = (int)((blockIdx.x * 256 + threadIdx.x) >> 6);  // class id
    const int lane = threadIdx.x & 63;

    const f32x4* c4 = (const f32x4*)(centers + (size_t)w * FEAT);
    const f32x4 a0 = c4[lane];
    const f32x4 a1 = c4[lane + 64];

    f32x4 S0 = {0.f,0.f,0.f,0.f}, S1 = {0.f,0.f,0.f,0.f};
    float loss = 0.0f;
    int cnt = 0;
    for (int j = __builtin_amdgcn_readfirstlane(head[w]); j >= 0;
         j = __builtin_amdgcn_readfirstlane(next[j]), ++cnt) {
        const f32x4* f4 = (const f32x4*)(features + (size_t)j * FEAT);
        const f32x4 f0 = __builtin_nontemporal_load(f4 + lane);       // stream once
        const f32x4 f1 = __builtin_nontemporal_load(f4 + lane + 64);
        S0 += f0; S1 += f1;
        const f32x4 d0 = f0 - a0, d1 = f1 - a1;
        loss += d0.x*d0.x + d0.y*d0.y + d0.z*d0.z + d0.w*d0.w
              + d1.x*d1.x + d1.y*d1.y + d1.z*d1.z + d1.w*d1.w;
    }

    f32x4 n0, n1;
    if (cnt > 0) {
        const float s = 1.0f - ALPHA_F;
        const float v = ALPHA_F / (float)cnt;
        n0 = a0 * s + S0 * v;
        n1 = a1 * s + S1 * v;
    } else { n0 = a0; n1 = a1; }

#pragma unroll
    for (int off = 32; off > 0; off >>= 1)
        loss += __shfl_down(loss, off);
    if (lane == 0 && cnt > 0)
        atomicAdd(&bins[w & (NBINS - 1)], loss);

    store_row(out + 1 + (size_t)w * FEAT, n0, n1, lane);

    // ---- fused finalize: last block to finish reduces the 256 bins ----
    __threadfence();
    __syncthreads();
    __shared__ int lastFlag;
    if (threadIdx.x == 0)
        lastFlag = (atomicAdd(done, 1) == (int)gridDim.x - 1) ? 1 : 0;
    __syncthreads();
    if (lastFlag) {
        __threadfence();
        const int t = threadIdx.x;          // 256 threads = NBINS
        float s = __hip_atomic_load(&bins[t], __ATOMIC_RELAXED,
                                    __HIP_MEMORY_SCOPE_AGENT);
#pragma unroll
        for (int off = 32; off > 0; off >>= 1)
            s += __shfl_down(s, off);
        __shared__ float sm[4];
        if ((t & 63) == 0) sm[t >> 6] = s;
        __syncthreads();
        if (t == 0) out[0] = (sm[0] + sm[1] + sm[2] + sm[3]) / (float)B;
    }
}

extern "C" void kernel_launch(void* const* d_in, const int* in_sizes, int n_in,
                              void* d_out, int out_size, void* d_ws, size_t ws_size,
                              hipStream_t stream) {
    const float* features = (const float*)d_in[0];
    const int*   labels   = (const int*)d_in[1];
    const float* centers  = (const float*)d_in[2];

    float* out  = (float*)d_out;
    int*   head = (int*)d_ws;               // NCLS
    int*   next = head + NCLS;              // B
    float* bins = (float*)(next + B);       // NBINS
    int*   done = (int*)(bins + NBINS);     // 1

    hipMemsetAsync(head, 0xFF, NCLS * sizeof(int), stream);   // head[c] = -1
    k_build<<<B / 256, 256, 0, stream>>>(labels, head, next, bins, done);
    k_class<<<NCLS / 4, 256, 0, stream>>>(centers, features, head, next, out, bins, done);
}

// Round 6
// 47.655 us; speedup vs baseline: 29.9797x; 29.9797x over previous
//
#include <hip/hip_runtime.h>

constexpr int FEAT = 512;          // feature dim
constexpr int NCLS = 50000;        // classes
constexpr int B    = 8192;         // batch
constexpr float ALPHA_F = 0.1f;
constexpr int NBINS = 256;

typedef float f32x4 __attribute__((ext_vector_type(4)));

// ---------------------------------------------------------------------------
// ws layout (4B elems):
//   [0, NCLS)          head  (int)   per-class list head, -1 = empty
//   [NCLS, NCLS+B)     next  (int)   linked list
//   [NCLS+B, +NBINS)   bins  (float) loss partial bins
// ---------------------------------------------------------------------------

__global__ void k_init(int* __restrict__ head, float* __restrict__ bins) {
    int i = blockIdx.x * blockDim.x + threadIdx.x;
    if (i < NCLS / 4) ((int4*)head)[i] = make_int4(-1, -1, -1, -1);
    if (i < NBINS) bins[i] = 0.0f;
}

__global__ void k_build(const int* __restrict__ labels,
                        int* __restrict__ head, int* __restrict__ next) {
    int i = blockIdx.x * blockDim.x + threadIdx.x;
    if (i < B) next[i] = atomicExch(&head[labels[i]], i);
}

// One wave per class. Walk the class's row list (uniform across lanes),
// accumulate sum(features) + squared-diff loss, write new center row
// (realigned by +1 dword via shfl so stores are float4).
__global__ void __launch_bounds__(256)
k_class(const float* __restrict__ centers,
        const float* __restrict__ features,
        const int* __restrict__ head,
        const int* __restrict__ next,
        float* __restrict__ out,          // [0]=loss, +1 = new_centers
        float* __restrict__ bins) {
    const int wid  = (int)((blockIdx.x * 256 + threadIdx.x) >> 6);
    const int lane = threadIdx.x & 63;

    const f32x4* c4 = (const f32x4*)(centers + (size_t)wid * FEAT);
    const f32x4 a0 = c4[lane];
    const f32x4 a1 = c4[lane + 64];

    f32x4 S0 = {0.f,0.f,0.f,0.f}, S1 = {0.f,0.f,0.f,0.f};
    float loss = 0.0f;
    int cnt = 0;
    for (int j = __builtin_amdgcn_readfirstlane(head[wid]); j >= 0;
         j = __builtin_amdgcn_readfirstlane(next[j]), ++cnt) {
        const f32x4* f4 = (const f32x4*)(features + (size_t)j * FEAT);
        const f32x4 f0 = f4[lane];
        const f32x4 f1 = f4[lane + 64];
        S0 += f0; S1 += f1;
        const f32x4 d0 = f0 - a0, d1 = f1 - a1;
        loss += d0.x*d0.x + d0.y*d0.y + d0.z*d0.z + d0.w*d0.w
              + d1.x*d1.x + d1.y*d1.y + d1.z*d1.z + d1.w*d1.w;
    }

    f32x4 n0, n1;
    if (cnt > 0) {
        const float s = 1.0f - ALPHA_F;
        const float v = ALPHA_F / (float)cnt;
        n0 = a0 * s + S0 * v;
        n1 = a1 * s + S1 * v;
    } else { n0 = a0; n1 = a1; }

    // wave reduce loss, bin-atomic (only when nonzero)
#pragma unroll
    for (int off = 32; off > 0; off >>= 1)
        loss += __shfl_down(loss, off);
    if (lane == 0 && cnt > 0)
        atomicAdd(&bins[wid & (NBINS - 1)], loss);

    // ---- realigned store: output row = d_out dwords [1+512c, 513+512c) ----
    float* orow = out + 1 + (size_t)wid * FEAT;
    const float bx = __shfl(n1.x, 0);
    const float by = __shfl(n1.y, 0);
    const float bz = __shfl(n1.z, 0);
    float x0 = __shfl_down(n0.x, 1), y0 = __shfl_down(n0.y, 1), z0 = __shfl_down(n0.z, 1);
    float x1 = __shfl_down(n1.x, 1), y1 = __shfl_down(n1.y, 1), z1 = __shfl_down(n1.z, 1);
    if (lane == 63) { x0 = bx; y0 = by; z0 = bz; }

    if (lane == 0) { orow[0] = n0.x; orow[1] = n0.y; orow[2] = n0.z; }
    f32x4* oa = (f32x4*)(orow + 3);           // 16B aligned
    oa[lane] = (f32x4){n0.w, x0, y0, z0};
    if (lane < 63)
        oa[64 + lane] = (f32x4){n1.w, x1, y1, z1};
    if (lane == 63) orow[511] = n1.w;
}

__global__ void k_fin(const float* __restrict__ bins, float* __restrict__ out) {
    const int t = threadIdx.x;        // 256 threads = 4 waves
    float s = bins[t];
#pragma unroll
    for (int off = 32; off > 0; off >>= 1)
        s += __shfl_down(s, off);
    __shared__ float sm[4];
    if ((t & 63) == 0) sm[t >> 6] = s;
    __syncthreads();
    if (t == 0) out[0] = (sm[0] + sm[1] + sm[2] + sm[3]) / (float)B;
}

extern "C" void kernel_launch(void* const* d_in, const int* in_sizes, int n_in,
                              void* d_out, int out_size, void* d_ws, size_t ws_size,
                              hipStream_t stream) {
    const float* features = (const float*)d_in[0];
    const int*   labels   = (const int*)d_in[1];
    const float* centers  = (const float*)d_in[2];

    float* out  = (float*)d_out;
    int*   head = (int*)d_ws;             // NCLS
    int*   next = head + NCLS;            // B
    float* bins = (float*)(next + B);     // NBINS

    k_init<<<(NCLS + 255) / 256, 256, 0, stream>>>(head, bins);
    k_build<<<(B + 255) / 256, 256, 0, stream>>>(labels, head, next);
    k_class<<<NCLS / 4, 256, 0, stream>>>(centers, features, head, next, out, bins);
    k_fin<<<1, 256, 0, stream>>>(bins, out);
}

// Round 7
// 47.362 us; speedup vs baseline: 30.1653x; 1.0062x over previous
//
#include <hip/hip_runtime.h>

constexpr int FEAT = 512;          // feature dim
constexpr int NCLS = 50000;        // classes
constexpr int B    = 8192;         // batch
constexpr float ALPHA_F = 0.1f;
constexpr int NBINS = 256;

typedef float f32x4 __attribute__((ext_vector_type(4)));

// ---------------------------------------------------------------------------
// ws layout (4B elems):
//   [0, NCLS)          head  (int)   per-class list head, -1 = empty (memset 0xFF)
//   [NCLS, NCLS+B)     next  (int)   linked list
//   [NCLS+B, +NBINS)   bins  (float) loss partial bins (zeroed in k_build)
// ---------------------------------------------------------------------------

// grid = B threads exactly; also zeroes bins (read only by k_class, later)
__global__ void k_build(const int* __restrict__ labels,
                        int* __restrict__ head, int* __restrict__ next,
                        float* __restrict__ bins) {
    int i = blockIdx.x * blockDim.x + threadIdx.x;
    next[i] = atomicExch(&head[labels[i]], i);
    if (i < NBINS) bins[i] = 0.0f;
}

// One wave per class. Walk the class's row list (uniform across lanes),
// accumulate sum(features) + squared-diff loss, write new center row
// (realigned by +1 dword via shfl so stores are float4).
__global__ void __launch_bounds__(256)
k_class(const float* __restrict__ centers,
        const float* __restrict__ features,
        const int* __restrict__ head,
        const int* __restrict__ next,
        float* __restrict__ out,          // [0]=loss, +1 = new_centers
        float* __restrict__ bins) {
    const int wid  = (int)((blockIdx.x * 256 + threadIdx.x) >> 6);
    const int lane = threadIdx.x & 63;

    // start the dependent chain first; center loads fill its latency
    const int h = __builtin_amdgcn_readfirstlane(head[wid]);

    const f32x4* c4 = (const f32x4*)(centers + (size_t)wid * FEAT);
    const f32x4 a0 = c4[lane];
    const f32x4 a1 = c4[lane + 64];

    f32x4 S0 = {0.f,0.f,0.f,0.f}, S1 = {0.f,0.f,0.f,0.f};
    float loss = 0.0f;
    int cnt = 0;
    for (int j = h; j >= 0;
         j = __builtin_amdgcn_readfirstlane(next[j]), ++cnt) {
        const f32x4* f4 = (const f32x4*)(features + (size_t)j * FEAT);
        const f32x4 f0 = f4[lane];
        const f32x4 f1 = f4[lane + 64];
        S0 += f0; S1 += f1;
        const f32x4 d0 = f0 - a0, d1 = f1 - a1;
        loss += d0.x*d0.x + d0.y*d0.y + d0.z*d0.z + d0.w*d0.w
              + d1.x*d1.x + d1.y*d1.y + d1.z*d1.z + d1.w*d1.w;
    }

    f32x4 n0, n1;
    if (cnt > 0) {
        const float s = 1.0f - ALPHA_F;
        const float v = ALPHA_F / (float)cnt;
        n0 = a0 * s + S0 * v;
        n1 = a1 * s + S1 * v;
        // wave reduce loss + bin atomic (only classes with samples)
#pragma unroll
        for (int off = 32; off > 0; off >>= 1)
            loss += __shfl_down(loss, off);
        if (lane == 0)
            atomicAdd(&bins[wid & (NBINS - 1)], loss);
    } else { n0 = a0; n1 = a1; }

    // ---- realigned store: output row = d_out dwords [1+512c, 513+512c) ----
    float* orow = out + 1 + (size_t)wid * FEAT;
    const float bx = __shfl(n1.x, 0);
    const float by = __shfl(n1.y, 0);
    const float bz = __shfl(n1.z, 0);
    float x0 = __shfl_down(n0.x, 1), y0 = __shfl_down(n0.y, 1), z0 = __shfl_down(n0.z, 1);
    float x1 = __shfl_down(n1.x, 1), y1 = __shfl_down(n1.y, 1), z1 = __shfl_down(n1.z, 1);
    if (lane == 63) { x0 = bx; y0 = by; z0 = bz; }

    if (lane == 0) { orow[0] = n0.x; orow[1] = n0.y; orow[2] = n0.z; }
    f32x4* oa = (f32x4*)(orow + 3);           // 16B aligned
    oa[lane] = (f32x4){n0.w, x0, y0, z0};
    if (lane < 63)
        oa[64 + lane] = (f32x4){n1.w, x1, y1, z1};
    if (lane == 63) orow[511] = n1.w;
}

__global__ void k_fin(const float* __restrict__ bins, float* __restrict__ out) {
    const int t = threadIdx.x;        // 256 threads = 4 waves
    float s = bins[t];
#pragma unroll
    for (int off = 32; off > 0; off >>= 1)
        s += __shfl_down(s, off);
    __shared__ float sm[4];
    if ((t & 63) == 0) sm[t >> 6] = s;
    __syncthreads();
    if (t == 0) out[0] = (sm[0] + sm[1] + sm[2] + sm[3]) / (float)B;
}

extern "C" void kernel_launch(void* const* d_in, const int* in_sizes, int n_in,
                              void* d_out, int out_size, void* d_ws, size_t ws_size,
                              hipStream_t stream) {
    const float* features = (const float*)d_in[0];
    const int*   labels   = (const int*)d_in[1];
    const float* centers  = (const float*)d_in[2];

    float* out  = (float*)d_out;
    int*   head = (int*)d_ws;             // NCLS
    int*   next = head + NCLS;            // B
    float* bins = (float*)(next + B);     // NBINS

    hipMemsetAsync(head, 0xFF, NCLS * sizeof(int), stream);   // head[c] = -1
    k_build<<<B / 256, 256, 0, stream>>>(labels, head, next, bins);
    k_class<<<NCLS / 4, 256, 0, stream>>>(centers, features, head, next, out, bins);
    k_fin<<<1, 256, 0, stream>>>(bins, out);
}